// Round 18
// baseline (226.935 us; speedup 1.0000x reference)
//
#include <hip/hip_runtime.h>

// Binarized conv block via i8 MFMA implicit GEMM — ZERO-LDS direct-register.
//   a = sign(x+bias1) in {+1,-1} (i8), zero-padded image [32][58][58][256] i8
//   qk = sign(kernel) in {+1,-1} (i8), pre-transposed to W_t[co][k]
//   conv == GEMM: C[pixel][co] = sum_k A_im2col[pixel][k] * W[k][co]
//   out = relu(C*scale[co] + shift[co])
//
// R8-R17: ten LDS-staged barrier schedules all pinned at 22-30% MfmaUtil;
// cycle audit shows ~33% irreducible sync/latency exposure shared by ALL
// barrier-locked structures. R18 deletes the mechanism: fragments are loaded
// DIRECTLY global->VGPR (A-frag reads are coalesced 16x64B segments; B is a
// 576KB L2-resident panel; the 4 waves of a block read IDENTICAL A addresses
// -> L1 broadcast). No __shared__, no barriers, no waitcnt asm — each wave
// fully independent, named double-buffered frag sets (static indices only),
// 1-tile prefetch lead (~650cyc MFMA) >> L1/L2 latency.

typedef int v4i __attribute__((ext_vector_type(4)));
typedef unsigned int u32;

#define NB   32
#define HW   56
#define HP   58
#define HP2  (HP*HP)             // 3364
#define CIN  256
#define COUT 256
#define NPIX (NB*HW*HW)          // 100352
#define KTOT 2304
#define BM   128                 // pixels per block (and per wave)
#define NSTEP 36                 // K tiles of 64
#define NWG  (NPIX/BM)           // 784 = 8*98

#define PA_BYTES ((size_t)NB*HP*HP*CIN)     // 27,557,888
#define WT_OFF   PA_BYTES
#define WT_BYTES ((size_t)KTOT*COUT)        // 589,824
#define SC_OFF   (WT_OFF + WT_BYTES)
#define SH_OFF   (SC_OFF + 1024)

// ------- pack activations incl. pad ring: sign(x+bias1) or 0 -> i8 -------
__global__ __launch_bounds__(256) void pack_a_kernel(
    const float* __restrict__ x, const float* __restrict__ b1,
    signed char* __restrict__ pa)
{
    const int lane = threadIdx.x & 63;
    const int pp = blockIdx.x * 4 + (threadIdx.x >> 6);   // padded pixel
    const int n = pp / HP2, r = pp % HP2, ph = r / HP, pw = r % HP;
    const int ci = lane * 4;
    u32 o = 0;
    if (ph >= 1 && ph <= HW && pw >= 1 && pw <= HW) {     // wave-uniform branch
        const int pix = (n * HW + ph - 1) * HW + (pw - 1);
        const float4 xv = *(const float4*)(x + (size_t)pix * CIN + ci);
        const float4 bv = *(const float4*)(b1 + ci);
        o  = (u32)(unsigned char)((xv.x + bv.x >= 0.f) ? 1 : -1);
        o |= (u32)(unsigned char)((xv.y + bv.y >= 0.f) ? 1 : -1) << 8;
        o |= (u32)(unsigned char)((xv.z + bv.z >= 0.f) ? 1 : -1) << 16;
        o |= (u32)(unsigned char)((xv.w + bv.w >= 0.f) ? 1 : -1) << 24;
    }
    *(u32*)(pa + (size_t)pp * CIN + ci) = o;
    // grid = NB*HP*HP/4 = 26912
}

// ---------------- pack + transpose weights: W_t[co][k] i8 ----------------
__global__ __launch_bounds__(256) void packw_kernel(
    const float* __restrict__ k, signed char* __restrict__ wt)
{
    __shared__ signed char tile[64][256];
    const int t = threadIdx.x, k0 = blockIdx.x * 64;
    for (int j = 0; j < 64; ++j)
        tile[j][t] = (k[(size_t)(k0 + j) * COUT + t] >= 0.f) ? 1 : -1;
    __syncthreads();
    u32 wd[16];
#pragma unroll
    for (int j = 0; j < 16; ++j) wd[j] = 0;
#pragma unroll
    for (int j = 0; j < 64; ++j)
        wd[j >> 2] |= ((u32)(unsigned char)tile[j][t]) << ((j & 3) * 8);
    uint4* dst = (uint4*)(wt + (size_t)t * KTOT + k0);
#pragma unroll
    for (int j = 0; j < 4; ++j)
        dst[j] = make_uint4(wd[4*j], wd[4*j+1], wd[4*j+2], wd[4*j+3]);
    // grid = KTOT/64 = 36
}

// ---------------- fold BN + bias2 ----------------
__global__ __launch_bounds__(256) void bnprep_kernel(
    const float* __restrict__ beta, const float* __restrict__ mean,
    const float* __restrict__ var, const float* __restrict__ b2,
    float* __restrict__ scale, float* __restrict__ shift)
{
    const int t = threadIdx.x;
    const float s = rsqrtf(var[t] + 1e-3f);
    scale[t] = s;
    shift[t] = beta[t] - mean[t] * s + b2[t];
}

// ---------------- i8 implicit-GEMM conv + BN + relu (direct-reg) ----------
// 256 thr = 4 independent waves; block = 128px x 256co; wave w owns
// 128px x couts [w*64, w*64+64): acc[8][4], 32 mfma per K-tile of 64.
// A addresses identical across the 4 waves -> L1 broadcast.

// load one K-tile's fragments straight into named register sets
#define LOAD_TILE(AF, BF, S)                                                  \
    {                                                                         \
        const int tap_ = (S) >> 2, cq_ = (S) & 3;                             \
        const u32 gA_ = (u32)((((tap_ / 3) * HP + (tap_ % 3)) << 8) + (cq_ << 6)); \
        const u32 gB_ = (u32)((S) << 6);                                      \
        _Pragma("unroll")                                                     \
        for (int pg = 0; pg < 8; ++pg)                                        \
            AF[pg] = *(const v4i*)(pa + aB[pg] + gA_);                        \
        _Pragma("unroll")                                                     \
        for (int cg = 0; cg < 4; ++cg)                                        \
            BF[cg] = *(const v4i*)(wt + bB[cg] + gB_);                        \
    }

#define MFMA_TILE(AF, BF)                                                     \
    _Pragma("unroll")                                                         \
    for (int pg = 0; pg < 8; ++pg) {                                          \
        _Pragma("unroll")                                                     \
        for (int cg = 0; cg < 4; ++cg)                                        \
            acc[pg][cg] = __builtin_amdgcn_mfma_i32_16x16x64_i8(              \
                AF[pg], BF[cg], acc[pg][cg], 0, 0, 0);                        \
    }

__global__ __launch_bounds__(256, 2) void conv_mfma_kernel(
    const signed char* __restrict__ pa, const signed char* __restrict__ wt,
    const float* __restrict__ scale, const float* __restrict__ shift,
    float* __restrict__ out)
{
    const int t = threadIdx.x, l = t & 63, w = t >> 6;   // wave 0..3
    // XCD swizzle (784 = 8 x 98, bijective)
    const int swz = (blockIdx.x & 7) * (NWG / 8) + (blockIdx.x >> 3);
    const int p0 = swz * BM;

    // per-lane byte offsets: A row pg -> pixel p0 + pg*16 + (l&15), chunk l>>4
    u32 aB[8], bB[4];
#pragma unroll
    for (int pg = 0; pg < 8; ++pg) {
        const int p = p0 + pg * 16 + (l & 15);
        const int n = p / 3136, r = p % 3136, h = r / 56, ww = r % 56;
        aB[pg] = (u32)(((n * HP + h) * HP + ww) * CIN + ((l >> 4) << 4));
    }
#pragma unroll
    for (int cg = 0; cg < 4; ++cg) {
        const int co = w * 64 + cg * 16 + (l & 15);
        bB[cg] = (u32)(co * KTOT + ((l >> 4) << 4));
    }

    v4i acc[8][4];
#pragma unroll
    for (int i = 0; i < 8; ++i)
#pragma unroll
        for (int j = 0; j < 4; ++j) acc[i][j] = (v4i){0, 0, 0, 0};

    // named double-buffered fragment sets (all indices static after unroll)
    v4i aX[8], bX[4], aY[8], bY[4];

    LOAD_TILE(aX, bX, 0)
#pragma unroll 1
    for (int s = 0; s < NSTEP; s += 2) {
        LOAD_TILE(aY, bY, s + 1)              // prefetch s+1 (NSTEP even)
        MFMA_TILE(aX, bX)                     // compute s (hides load latency)
        if (s + 2 < NSTEP) LOAD_TILE(aX, bX, s + 2)
        MFMA_TILE(aY, bY)                     // compute s+1
    }

    // epilogue: C col = l&15 (co), row = (l>>4)*4 + reg (pixel)   [m89 layout]
#pragma unroll
    for (int cg = 0; cg < 4; ++cg) {
        const int co = w * 64 + cg * 16 + (l & 15);
        const float sc = scale[co], sh = shift[co];
#pragma unroll
        for (int pg = 0; pg < 8; ++pg) {
            const int prow0 = p0 + pg * 16 + (l >> 4) * 4;
#pragma unroll
            for (int rr = 0; rr < 4; ++rr) {
                const float y = (float)acc[pg][cg][rr];
                out[(size_t)(prow0 + rr) * COUT + co] = fmaxf(fmaf(y, sc, sh), 0.f);
            }
        }
    }
}

extern "C" void kernel_launch(void* const* d_in, const int* in_sizes, int n_in,
                              void* d_out, int out_size, void* d_ws, size_t ws_size,
                              hipStream_t stream)
{
    const float* x      = (const float*)d_in[0];
    const float* bias1  = (const float*)d_in[1];
    const float* kernel = (const float*)d_in[2];
    const float* bn_beta = (const float*)d_in[3];
    const float* bn_mean = (const float*)d_in[4];
    const float* bn_var  = (const float*)d_in[5];
    const float* bias2   = (const float*)d_in[6];
    float* out = (float*)d_out;

    signed char* pa  = (signed char*)d_ws;                // padded i8 image
    signed char* wtp = (signed char*)d_ws + WT_OFF;       // W_t[co][k]
    float* scale = (float*)((char*)d_ws + SC_OFF);
    float* shift = (float*)((char*)d_ws + SH_OFF);

    pack_a_kernel<<<dim3(NB * HP2 / 4), dim3(256), 0, stream>>>(x, bias1, pa);
    packw_kernel<<<dim3(KTOT / 64), dim3(256), 0, stream>>>(kernel, wtp);
    bnprep_kernel<<<dim3(1), dim3(256), 0, stream>>>(bn_beta, bn_mean, bn_var, bias2,
                                                     scale, shift);
    conv_mfma_kernel<<<dim3(NWG), dim3(256), 0, stream>>>(pa, wtp, scale, shift, out);
}

// Round 19
// 102.812 us; speedup vs baseline: 2.2073x; 2.2073x over previous
//
#include <hip/hip_runtime.h>

// Binarized conv block via i8 MFMA implicit GEMM.  == R14, the session best ==
//   a = sign(x+bias1) in {+1,-1} (i8), zero-padded image [32][58][58][256] i8
//   qk = sign(kernel) in {+1,-1} (i8), pre-transposed to W_t[co][k]
//   conv == GEMM: C[pixel][co] = sum_k A_im2col[pixel][k] * W[k][co]
//   out = relu(C*scale[co] + shift[co])   (folded BN + bias2)
// i8 zero-pad == true conv zero-pad -> exact integers, no edge corrections.
//
// Session ledger (R3-R18): popcount path HW-floored at 143us (v_bcnt rate);
// 11 MFMA schedules (2-phase / 8-phase / 3-deep counted-vmcnt / 4-wave /
// 8-wave / 3 tile shapes / zero-LDS direct-reg) all pin at 22-30% MfmaUtil —
// the 2-phase structural wall (m233). Best = THIS config: BK=128 (32-MFMA
// clusters, 18 steps), 2x2 wave grid (min LDS fragment traffic), stage-early
// + ONE vmcnt(0)+barrier per step, setprio cluster, XCD-swizzle (FETCH 19MB).
// conv 82.4us @ MfmaUtil 30%, total 102.9us, absmax 0.0.

typedef int v4i __attribute__((ext_vector_type(4)));
typedef unsigned int u32;

#define NB   32
#define HW   56
#define HP   58
#define HP2  (HP*HP)             // 3364
#define CIN  256
#define COUT 256
#define NPIX (NB*HW*HW)          // 100352
#define KTOT 2304
#define BM   128                 // pixels per block
#define BN   128                 // couts per block
#define NSTEP 18                 // K steps of 128 (2 x 64-chunks)
#define NWG  ((NPIX/BM)*(COUT/BN))   // 1568 = 8*196

#define PA_BYTES ((size_t)NB*HP*HP*CIN)     // 27,557,888
#define WT_OFF   PA_BYTES
#define WT_BYTES ((size_t)KTOT*COUT)        // 589,824
#define SC_OFF   (WT_OFF + WT_BYTES)
#define SH_OFF   (SC_OFF + 1024)

__device__ __forceinline__ void g2l16(const void* g, void* l) {
    __builtin_amdgcn_global_load_lds(
        (const __attribute__((address_space(1))) void*)g,
        (__attribute__((address_space(3))) void*)l, 16, 0, 0);
}

// ------- pack activations incl. pad ring: sign(x+bias1) or 0 -> i8 -------
__global__ __launch_bounds__(256) void pack_a_kernel(
    const float* __restrict__ x, const float* __restrict__ b1,
    signed char* __restrict__ pa)
{
    const int lane = threadIdx.x & 63;
    const int pp = blockIdx.x * 4 + (threadIdx.x >> 6);   // padded pixel
    const int n = pp / HP2, r = pp % HP2, ph = r / HP, pw = r % HP;
    const int ci = lane * 4;
    u32 o = 0;
    if (ph >= 1 && ph <= HW && pw >= 1 && pw <= HW) {     // wave-uniform branch
        const int pix = (n * HW + ph - 1) * HW + (pw - 1);
        const float4 xv = *(const float4*)(x + (size_t)pix * CIN + ci);
        const float4 bv = *(const float4*)(b1 + ci);
        o  = (u32)(unsigned char)((xv.x + bv.x >= 0.f) ? 1 : -1);
        o |= (u32)(unsigned char)((xv.y + bv.y >= 0.f) ? 1 : -1) << 8;
        o |= (u32)(unsigned char)((xv.z + bv.z >= 0.f) ? 1 : -1) << 16;
        o |= (u32)(unsigned char)((xv.w + bv.w >= 0.f) ? 1 : -1) << 24;
    }
    *(u32*)(pa + (size_t)pp * CIN + ci) = o;
    // grid = NB*HP*HP/4 = 26912
}

// ---------------- pack + transpose weights: W_t[co][k] i8 ----------------
__global__ __launch_bounds__(256) void packw_kernel(
    const float* __restrict__ k, signed char* __restrict__ wt)
{
    __shared__ signed char tile[64][256];
    const int t = threadIdx.x, k0 = blockIdx.x * 64;
    for (int j = 0; j < 64; ++j)
        tile[j][t] = (k[(size_t)(k0 + j) * COUT + t] >= 0.f) ? 1 : -1;
    __syncthreads();
    u32 wd[16];
#pragma unroll
    for (int j = 0; j < 16; ++j) wd[j] = 0;
#pragma unroll
    for (int j = 0; j < 64; ++j)
        wd[j >> 2] |= ((u32)(unsigned char)tile[j][t]) << ((j & 3) * 8);
    uint4* dst = (uint4*)(wt + (size_t)t * KTOT + k0);
#pragma unroll
    for (int j = 0; j < 4; ++j)
        dst[j] = make_uint4(wd[4*j], wd[4*j+1], wd[4*j+2], wd[4*j+3]);
    // grid = KTOT/64 = 36
}

// ---------------- fold BN + bias2 ----------------
__global__ __launch_bounds__(256) void bnprep_kernel(
    const float* __restrict__ beta, const float* __restrict__ mean,
    const float* __restrict__ var, const float* __restrict__ b2,
    float* __restrict__ scale, float* __restrict__ shift)
{
    const int t = threadIdx.x;
    const float s = rsqrtf(var[t] + 1e-3f);
    scale[t] = s;
    shift[t] = beta[t] - mean[t] * s + b2[t];
}

// ---------------- i8 implicit-GEMM conv + BN + relu ----------------
// 256 thr = 2x2 wave grid; block = 128px x 128co; wave (vm,vn) owns
// 64px x 64co: acc[4][4], 32 mfma_i32_16x16x64_i8 per K-step of 128.
__global__ __launch_bounds__(256, 2) void conv_mfma_kernel(
    const signed char* __restrict__ pa, const signed char* __restrict__ wt,
    const float* __restrict__ scale, const float* __restrict__ shift,
    float* __restrict__ out)
{
    // per buffer: A = 2ksub x 128px x 64B (16KB), B = 2ksub x 128co x 64B (16KB)
    __shared__ signed char L[2][32768];

    const int t = threadIdx.x, l = t & 63, v = t >> 6;
    const int vm = v >> 1, vn = v & 1;
    // XCD swizzle (1568 = 8 x 196, bijective); co-halves of a tile adjacent
    const int swz  = (blockIdx.x & 7) * (NWG / 8) + (blockIdx.x >> 3);
    const int tile = swz >> 1;
    const int co0  = (swz & 1) << 7;
    const int p0 = tile * BM;

    // A staging: thread t stages 16B slot (t&3) of pixel q=(t>>2)+i*64
    const signed char* abase[2];
#pragma unroll
    for (int i = 0; i < 2; ++i) {
        const int q = (t >> 2) + i * 64;
        const int p = p0 + q;
        const int n = p / 3136, r = p % 3136, h = r / 56, w = r % 56;
        const int aswz = (((t & 3) ^ ((q >> 1) & 3)) << 4);  // source pre-swizzle
        abase[i] = pa + ((size_t)(n * HP + h) * HP + w) * CIN + aswz;
    }
    // B staging: thread t stages slot (t&3) of W-row r=(t>>2)+j*64
    const signed char* wbase[2];
#pragma unroll
    for (int j = 0; j < 2; ++j) {
        const int r = j * 64 + (t >> 2);
        const int bswz = (((t & 3) ^ ((r >> 1) & 3)) << 4);
        wbase[j] = wt + (size_t)(co0 + r) * KTOT + bswz;
    }

    // fragment ds_read byte offsets (swizzled reads match pre-swizzled src)
    int aoff[4], boff[4];
#pragma unroll
    for (int pg = 0; pg < 4; ++pg) {
        const int row = vm * 64 + pg * 16 + (l & 15);
        aoff[pg] = row * 64 + ((((l >> 4) ^ (row >> 1)) & 3) << 4);
    }
#pragma unroll
    for (int cg = 0; cg < 4; ++cg) {
        const int row = vn * 64 + cg * 16 + (l & 15);
        boff[cg] = 16384 + row * 64 + ((((l >> 4) ^ (row >> 1)) & 3) << 4);
    }

    v4i acc[4][4];
#pragma unroll
    for (int i = 0; i < 4; ++i)
#pragma unroll
        for (int j = 0; j < 4; ++j) acc[i][j] = (v4i){0, 0, 0, 0};

    auto goffA = [&](int k64) {
        const int tap = k64 >> 2, cq = k64 & 3;
        const int ty = tap / 3, tx = tap - ty * 3;
        return ((ty * HP + tx) << 8) + (cq << 6);
    };
    auto STAGE = [&](int buf, int s) {         // 8 g2l16 per thread
#pragma unroll
        for (int ks = 0; ks < 2; ++ks) {
            const int k64 = 2 * s + ks;
            const int go = goffA(k64);
            g2l16(abase[0] + go, &L[buf][ks * 8192 + v * 1024]);
            g2l16(abase[1] + go, &L[buf][ks * 8192 + 4096 + v * 1024]);
            g2l16(wbase[0] + (k64 << 6), &L[buf][16384 + ks * 8192 + v * 1024]);
            g2l16(wbase[1] + (k64 << 6), &L[buf][16384 + ks * 8192 + 4096 + v * 1024]);
        }
    };

    // prologue
    STAGE(0, 0);
    asm volatile("s_waitcnt vmcnt(0)" ::: "memory");
    __builtin_amdgcn_s_barrier();

#pragma unroll 1
    for (int s = 0; s < NSTEP; ++s) {
        const int cur = s & 1, nxt = cur ^ 1;
        const signed char* Lc = &L[cur][0];
        if (s + 1 < NSTEP) STAGE(nxt, s + 1);  // issue early; lands by step end
        // read all fragments of cur (compiler inserts lgkmcnt before MFMA)
        v4i af[2][4], bf[2][4];
#pragma unroll
        for (int ks = 0; ks < 2; ++ks) {
#pragma unroll
            for (int pg = 0; pg < 4; ++pg)
                af[ks][pg] = *(const v4i*)(Lc + ks * 8192 + aoff[pg]);
#pragma unroll
            for (int cg = 0; cg < 4; ++cg)
                bf[ks][cg] = *(const v4i*)(Lc + ks * 8192 + boff[cg]);
        }
        __builtin_amdgcn_s_setprio(1);
#pragma unroll
        for (int ks = 0; ks < 2; ++ks)
#pragma unroll
            for (int pg = 0; pg < 4; ++pg)
#pragma unroll
                for (int cg = 0; cg < 4; ++cg)
                    acc[pg][cg] = __builtin_amdgcn_mfma_i32_16x16x64_i8(
                        af[ks][pg], bf[ks][cg], acc[pg][cg], 0, 0, 0);
        __builtin_amdgcn_s_setprio(0);
        // stage(s+1) landed + all waves done reading cur (reads precede MFMAs)
        asm volatile("s_waitcnt vmcnt(0)" ::: "memory");
        __builtin_amdgcn_s_barrier();
    }

    // epilogue: C col = l&15 (co), row = (l>>4)*4 + reg (pixel)   [m89 layout]
#pragma unroll
    for (int cg = 0; cg < 4; ++cg) {
        const int co = co0 + vn * 64 + cg * 16 + (l & 15);
        const float sc = scale[co], sh = shift[co];
#pragma unroll
        for (int pg = 0; pg < 4; ++pg) {
            const int prow0 = p0 + vm * 64 + pg * 16 + (l >> 4) * 4;
#pragma unroll
            for (int rr = 0; rr < 4; ++rr) {
                const float y = (float)acc[pg][cg][rr];
                out[(size_t)(prow0 + rr) * COUT + co] = fmaxf(fmaf(y, sc, sh), 0.f);
            }
        }
    }
}

extern "C" void kernel_launch(void* const* d_in, const int* in_sizes, int n_in,
                              void* d_out, int out_size, void* d_ws, size_t ws_size,
                              hipStream_t stream)
{
    const float* x      = (const float*)d_in[0];
    const float* bias1  = (const float*)d_in[1];
    const float* kernel = (const float*)d_in[2];
    const float* bn_beta = (const float*)d_in[3];
    const float* bn_mean = (const float*)d_in[4];
    const float* bn_var  = (const float*)d_in[5];
    const float* bias2   = (const float*)d_in[6];
    float* out = (float*)d_out;

    signed char* pa  = (signed char*)d_ws;                // padded i8 image
    signed char* wtp = (signed char*)d_ws + WT_OFF;       // W_t[co][k]
    float* scale = (float*)((char*)d_ws + SC_OFF);
    float* shift = (float*)((char*)d_ws + SH_OFF);

    pack_a_kernel<<<dim3(NB * HP2 / 4), dim3(256), 0, stream>>>(x, bias1, pa);
    packw_kernel<<<dim3(KTOT / 64), dim3(256), 0, stream>>>(kernel, wtp);
    bnprep_kernel<<<dim3(1), dim3(256), 0, stream>>>(bn_beta, bn_mean, bn_var, bias2,
                                                     scale, shift);
    conv_mfma_kernel<<<dim3(NWG), dim3(256), 0, stream>>>(pa, wtp, scale, shift, out);
}

// Round 20
// 98.993 us; speedup vs baseline: 2.2924x; 1.0386x over previous
//
#include <hip/hip_runtime.h>

// Binarized conv block via i8 MFMA implicit GEMM.  == R14 + B-direct ==
//   a = sign(x+bias1) in {+1,-1} (i8), zero-padded image [32][58][58][256] i8
//   qk = sign(kernel) in {+1,-1} (i8), packed to FRAGMENT order wf[k64][ch][co]
//   conv == GEMM: C[pixel][co] = sum_k A_im2col[pixel][k] * W[k][co]
//   out = relu(C*scale[co] + shift[co])   (folded BN + bias2)
//
// R14 audit: LDS pipe (reads+writes) = 96KB/block-step = ~51us/CU floor —
// the dominant term under conv=82us. R20: B never touches LDS. W is packed
// in fragment order (16B unit (k64,chunk,co) at ((k64*4+ch)*256+co)*16) so
// each wave's B-fragment is a near-coalesced global read of the L2-resident
// 576KB panel, issued alongside the A ds_reads. LDS halves (32KB, A-only,
// 48KB traffic/block-step -> ~25us floor). A path, schedule, XCD swizzle,
// epilogue byte-identical to R14 (conv 82.4us / total 102.9 / absmax 0.0).

typedef int v4i __attribute__((ext_vector_type(4)));
typedef unsigned int u32;

#define NB   32
#define HW   56
#define HP   58
#define HP2  (HP*HP)             // 3364
#define CIN  256
#define COUT 256
#define NPIX (NB*HW*HW)          // 100352
#define KTOT 2304
#define BM   128                 // pixels per block
#define BN   128                 // couts per block
#define NSTEP 18                 // K steps of 128 (2 x 64-chunks)
#define NWG  ((NPIX/BM)*(COUT/BN))   // 1568 = 8*196

#define PA_BYTES ((size_t)NB*HP*HP*CIN)     // 27,557,888
#define WT_OFF   PA_BYTES
#define WT_BYTES ((size_t)KTOT*COUT)        // 589,824
#define SC_OFF   (WT_OFF + WT_BYTES)
#define SH_OFF   (SC_OFF + 1024)

__device__ __forceinline__ void g2l16(const void* g, void* l) {
    __builtin_amdgcn_global_load_lds(
        (const __attribute__((address_space(1))) void*)g,
        (__attribute__((address_space(3))) void*)l, 16, 0, 0);
}

// ------- pack activations incl. pad ring: sign(x+bias1) or 0 -> i8 -------
__global__ __launch_bounds__(256) void pack_a_kernel(
    const float* __restrict__ x, const float* __restrict__ b1,
    signed char* __restrict__ pa)
{
    const int lane = threadIdx.x & 63;
    const int pp = blockIdx.x * 4 + (threadIdx.x >> 6);   // padded pixel
    const int n = pp / HP2, r = pp % HP2, ph = r / HP, pw = r % HP;
    const int ci = lane * 4;
    u32 o = 0;
    if (ph >= 1 && ph <= HW && pw >= 1 && pw <= HW) {     // wave-uniform branch
        const int pix = (n * HW + ph - 1) * HW + (pw - 1);
        const float4 xv = *(const float4*)(x + (size_t)pix * CIN + ci);
        const float4 bv = *(const float4*)(b1 + ci);
        o  = (u32)(unsigned char)((xv.x + bv.x >= 0.f) ? 1 : -1);
        o |= (u32)(unsigned char)((xv.y + bv.y >= 0.f) ? 1 : -1) << 8;
        o |= (u32)(unsigned char)((xv.z + bv.z >= 0.f) ? 1 : -1) << 16;
        o |= (u32)(unsigned char)((xv.w + bv.w >= 0.f) ? 1 : -1) << 24;
    }
    *(u32*)(pa + (size_t)pp * CIN + ci) = o;
    // grid = NB*HP*HP/4 = 26912
}

// ------- pack weights into FRAGMENT order: 16B unit (k64,ch,co) -------
// unit address = ((k64*4 + ch)*256 + co)*16 ; contains W k-values
// k64*64 + ch*16 .. +16 for output co (exactly the bytes the old LDS
// fragment read produced for lane group ch).
__global__ __launch_bounds__(256) void packw_kernel(
    const float* __restrict__ k, signed char* __restrict__ wf)
{
    __shared__ signed char tile[64][256];
    const int t = threadIdx.x, k0 = blockIdx.x * 64;      // k64 = blockIdx.x
    for (int j = 0; j < 64; ++j)
        tile[j][t] = (k[(size_t)(k0 + j) * COUT + t] >= 0.f) ? 1 : -1;
    __syncthreads();
    u32 wd[16];
#pragma unroll
    for (int j = 0; j < 16; ++j) wd[j] = 0;
#pragma unroll
    for (int j = 0; j < 64; ++j)
        wd[j >> 2] |= ((u32)(unsigned char)tile[j][t]) << ((j & 3) * 8);
#pragma unroll
    for (int c = 0; c < 4; ++c)
        *(uint4*)(wf + (((size_t)blockIdx.x * 4 + c) * 256 + t) * 16) =
            make_uint4(wd[4*c], wd[4*c+1], wd[4*c+2], wd[4*c+3]);
    // grid = KTOT/64 = 36
}

// ---------------- fold BN + bias2 ----------------
__global__ __launch_bounds__(256) void bnprep_kernel(
    const float* __restrict__ beta, const float* __restrict__ mean,
    const float* __restrict__ var, const float* __restrict__ b2,
    float* __restrict__ scale, float* __restrict__ shift)
{
    const int t = threadIdx.x;
    const float s = rsqrtf(var[t] + 1e-3f);
    scale[t] = s;
    shift[t] = beta[t] - mean[t] * s + b2[t];
}

// ---------------- i8 implicit-GEMM conv + BN + relu ----------------
// 256 thr = 2x2 wave grid; block = 128px x 128co; wave (vm,vn) owns
// 64px x 64co: acc[4][4], 32 mfma per K-step of 128. A via LDS (R14 path),
// B direct global->VGPR from the fragment-ordered L2-resident panel.
__global__ __launch_bounds__(256, 2) void conv_mfma_kernel(
    const signed char* __restrict__ pa, const signed char* __restrict__ wf,
    const float* __restrict__ scale, const float* __restrict__ shift,
    float* __restrict__ out)
{
    // per buffer: A = 2ksub x 128px x 64B = 16KB
    __shared__ signed char L[2][16384];

    const int t = threadIdx.x, l = t & 63, v = t >> 6;
    const int vm = v >> 1, vn = v & 1;
    // XCD swizzle (1568 = 8 x 196, bijective); co-halves of a tile adjacent
    const int swz  = (blockIdx.x & 7) * (NWG / 8) + (blockIdx.x >> 3);
    const int tile = swz >> 1;
    const int co0  = (swz & 1) << 7;
    const int p0 = tile * BM;

    // A staging: thread t stages 16B slot (t&3) of pixel q=(t>>2)+i*64
    const signed char* abase[2];
#pragma unroll
    for (int i = 0; i < 2; ++i) {
        const int q = (t >> 2) + i * 64;
        const int p = p0 + q;
        const int n = p / 3136, r = p % 3136, h = r / 56, w = r % 56;
        const int aswz = (((t & 3) ^ ((q >> 1) & 3)) << 4);  // source pre-swizzle
        abase[i] = pa + ((size_t)(n * HP + h) * HP + w) * CIN + aswz;
    }

    // A fragment ds_read offsets (swizzled reads match pre-swizzled src)
    int aoff[4];
#pragma unroll
    for (int pg = 0; pg < 4; ++pg) {
        const int row = vm * 64 + pg * 16 + (l & 15);
        aoff[pg] = row * 64 + ((((l >> 4) ^ (row >> 1)) & 3) << 4);
    }
    // B fragment global byte offsets (fragment-ordered panel)
    u32 boffg[4];
#pragma unroll
    for (int cg = 0; cg < 4; ++cg) {
        const int co = co0 + vn * 64 + cg * 16 + (l & 15);
        boffg[cg] = (u32)((((l >> 4) * 256) + co) * 16);
    }

    v4i acc[4][4];
#pragma unroll
    for (int i = 0; i < 4; ++i)
#pragma unroll
        for (int j = 0; j < 4; ++j) acc[i][j] = (v4i){0, 0, 0, 0};

    auto goffA = [&](int k64) {
        const int tap = k64 >> 2, cq = k64 & 3;
        const int ty = tap / 3, tx = tap - ty * 3;
        return ((ty * HP + tx) << 8) + (cq << 6);
    };
    auto STAGE = [&](int buf, int s) {         // 4 g2l16 per thread (A only)
#pragma unroll
        for (int ks = 0; ks < 2; ++ks) {
            const int k64 = 2 * s + ks;
            const int go = goffA(k64);
            g2l16(abase[0] + go, &L[buf][ks * 8192 + v * 1024]);
            g2l16(abase[1] + go, &L[buf][ks * 8192 + 4096 + v * 1024]);
        }
    };

    // prologue
    STAGE(0, 0);
    asm volatile("s_waitcnt vmcnt(0)" ::: "memory");
    __builtin_amdgcn_s_barrier();

#pragma unroll 1
    for (int s = 0; s < NSTEP; ++s) {
        const int cur = s & 1, nxt = cur ^ 1;
        const signed char* Lc = &L[cur][0];
        if (s + 1 < NSTEP) STAGE(nxt, s + 1);  // issue early; lands by step end
        // B fragments: direct global (L2-hot), issued with the A ds_reads
        v4i af[2][4], bf[2][4];
#pragma unroll
        for (int ks = 0; ks < 2; ++ks) {
            const u32 kbase = (u32)(2 * s + ks) * 16384;
#pragma unroll
            for (int cg = 0; cg < 4; ++cg)
                bf[ks][cg] = *(const v4i*)(wf + kbase + boffg[cg]);
#pragma unroll
            for (int pg = 0; pg < 4; ++pg)
                af[ks][pg] = *(const v4i*)(Lc + ks * 8192 + aoff[pg]);
        }
        __builtin_amdgcn_s_setprio(1);
#pragma unroll
        for (int ks = 0; ks < 2; ++ks)
#pragma unroll
            for (int pg = 0; pg < 4; ++pg)
#pragma unroll
                for (int cg = 0; cg < 4; ++cg)
                    acc[pg][cg] = __builtin_amdgcn_mfma_i32_16x16x64_i8(
                        af[ks][pg], bf[ks][cg], acc[pg][cg], 0, 0, 0);
        __builtin_amdgcn_s_setprio(0);
        // stage(s+1) landed + all waves done reading cur (reads precede MFMAs)
        asm volatile("s_waitcnt vmcnt(0)" ::: "memory");
        __builtin_amdgcn_s_barrier();
    }

    // epilogue: C col = l&15 (co), row = (l>>4)*4 + reg (pixel)   [m89 layout]
#pragma unroll
    for (int cg = 0; cg < 4; ++cg) {
        const int co = co0 + vn * 64 + cg * 16 + (l & 15);
        const float sc = scale[co], sh = shift[co];
#pragma unroll
        for (int pg = 0; pg < 4; ++pg) {
            const int prow0 = p0 + vm * 64 + pg * 16 + (l >> 4) * 4;
#pragma unroll
            for (int rr = 0; rr < 4; ++rr) {
                const float y = (float)acc[pg][cg][rr];
                out[(size_t)(prow0 + rr) * COUT + co] = fmaxf(fmaf(y, sc, sh), 0.f);
            }
        }
    }
}

extern "C" void kernel_launch(void* const* d_in, const int* in_sizes, int n_in,
                              void* d_out, int out_size, void* d_ws, size_t ws_size,
                              hipStream_t stream)
{
    const float* x      = (const float*)d_in[0];
    const float* bias1  = (const float*)d_in[1];
    const float* kernel = (const float*)d_in[2];
    const float* bn_beta = (const float*)d_in[3];
    const float* bn_mean = (const float*)d_in[4];
    const float* bn_var  = (const float*)d_in[5];
    const float* bias2   = (const float*)d_in[6];
    float* out = (float*)d_out;

    signed char* pa  = (signed char*)d_ws;                // padded i8 image
    signed char* wfp = (signed char*)d_ws + WT_OFF;       // fragment-ordered W
    float* scale = (float*)((char*)d_ws + SC_OFF);
    float* shift = (float*)((char*)d_ws + SH_OFF);

    pack_a_kernel<<<dim3(NB * HP2 / 4), dim3(256), 0, stream>>>(x, bias1, pa);
    packw_kernel<<<dim3(KTOT / 64), dim3(256), 0, stream>>>(kernel, wfp);
    bnprep_kernel<<<dim3(1), dim3(256), 0, stream>>>(bn_beta, bn_mean, bn_var, bias2,
                                                     scale, shift);
    conv_mfma_kernel<<<dim3(NWG), dim3(256), 0, stream>>>(pa, wfp, scale, shift, out);
}